// Round 13
// baseline (162.936 us; speedup 1.0000x reference)
//
#include <hip/hip_runtime.h>

// Problem constants
#define N_ROWS 131072    // 32*4096
#define D 64
#define K_CODES 1024

typedef _Float16 f16x8 __attribute__((ext_vector_type(8)));
typedef float    f32x4 __attribute__((ext_vector_type(4)));

#define MFMA16(a, b, c) __builtin_amdgcn_mfma_f32_16x16x32_f16((a), (b), (c), 0, 0, 0)

// ---------------------------------------------------------------------------
// FUSED single kernel (prep eliminated). R12 post-mortem: pinned pipeline
// regressed (74.6 vs R10's 64.9us) — m141 lesson; per-wave-depth falsified.
// Recalibrated model: MFMA cost is per-SIMD ~19.4 cyc -> R10's demand
// 59.6k/156k cyc = 38% ~= measured 33% MfmaUtil: the consume loop runs at
// ~85-90% of its latency-structure ceiling; 8 structural variants at the
// same 33% plateau. Remaining certain win: the bench pays a second launch
// + prep exec every iteration (bench ~= 2*argmin + 13-16us). This kernel
// fuses prep: stage phase converts raw CB -> split(-2c) f16 fragments in
// LDS (same layout math as old prep, verified rounds 2-10), csqr slice
// recomputed per pass by t<256 (L2-dup reads, 12% L2 util -> free), loss
// zeroed by a 4B hipMemsetAsync (harness reset uses the same API).
// Macro-structure = R10 verbatim (measured 64.9us): 512 thr = 8 waves x
// 32 rows (MT=2) = 256 rows/block, grid 512 = 2 blocks/CU, 4 passes x
// 16 tiles, single 64KB buffer, free-run consume, 8 barriers total.
// __launch_bounds__(512,2) (128-reg cap) for conversion transients.
// Numerics: dist = |c|^2 + x.(-2c) via hh,hh,lh,lh,hl,hl (ll ~2^-24
// dropped), acc-init = csqr (identical accumulation order to old prep).
// Tie-break = global first-min: codes ascend with (p,tile) in-lane
// (strict <); 16-lane column reduce index-lexicographic. zq/loss epilogue
// verbatim from R10 (correctness-verified).
// ---------------------------------------------------------------------------
__global__ __launch_bounds__(512, 2)
void argmin_kernel(const float* __restrict__ X,
                   const float* __restrict__ CB,
                   float* __restrict__ out) {
    __shared__ _Float16 Bbuf[16][2048];   // 64 KB: 16 tiles x 4 KB (one pass)
    __shared__ float LsC[K_CODES];        // csqr, filled slice-per-pass
    __shared__ int   ivfin[256];
    __shared__ float lsum[8];

    const int t    = threadIdx.x;         // 0..511
    const int wave = t >> 6;              // 0..7
    const int lane = t & 63;
    const int quad = lane >> 4;
    const int lrow = lane & 15;
    const int R0   = blockIdx.x * 256;
    const int Rw   = R0 + wave * 32;      // this wave's 32 rows

// Stage pass p_: build the 16 tiles' B fragments directly from CB.
// Thread t handles 4 (tile, k-chunk) pairs: pi = (t>>6) + 8*j, tile = pi>>1,
// fb = pi&1; per pair load 8 f32 of code row (code = p*256 + tile*16 +
// lrow, cols fb*32 + quad*8 ..+8), convert sv = -2c to hi/lo f16, write
// the hi unit (f=fb) and lo unit (f=fb+2) at u_local = tile*256 + f*64 +
// lane (x16B) — byte-identical layout to the old prep's CBf (verified
// rounds 2-10). Also: t<256 recompute csqr for code p*256+t into LsC
// (same 16-float4 accumulation order as old prep).
#define STAGE_CONV(p_)                                                        \
    do {                                                                      \
        _Pragma("unroll")                                                     \
        for (int j_ = 0; j_ < 4; ++j_) {                                      \
            const int pi_ = (t >> 6) + 8 * j_;                                \
            const int i_  = pi_ >> 1;                                         \
            const int fb_ = pi_ & 1;                                          \
            const int code_ = (p_) * 256 + i_ * 16 + lrow;                    \
            const int k0_   = fb_ * 32 + quad * 8;                            \
            const float* src_ = CB + (size_t)code_ * D + k0_;                 \
            float4 v0_ = *(const float4*)(src_);                              \
            float4 v1_ = *(const float4*)(src_ + 4);                          \
            float xs_[8] = {v0_.x, v0_.y, v0_.z, v0_.w,                       \
                            v1_.x, v1_.y, v1_.z, v1_.w};                      \
            f16x8 h_, l_;                                                     \
            _Pragma("unroll")                                                 \
            for (int e_ = 0; e_ < 8; ++e_) {                                  \
                float sv_ = -2.0f * xs_[e_];                                  \
                _Float16 hh_ = (_Float16)sv_;                                 \
                h_[e_] = hh_;                                                 \
                l_[e_] = (_Float16)(sv_ - (float)hh_);                        \
            }                                                                 \
            _Float16* b_ = &Bbuf[0][0];                                       \
            *(f16x8*)(b_ + ((size_t)((i_ * 4 + fb_) * 64 + lane)) * 8) = h_;  \
            *(f16x8*)(b_ + ((size_t)((i_ * 4 + fb_ + 2) * 64 + lane)) * 8)    \
                = l_;                                                         \
        }                                                                     \
        if (t < 256) {                                                        \
            const int c_ = (p_) * 256 + t;                                    \
            const float4* q_ = (const float4*)(CB + (size_t)c_ * D);          \
            float s_ = 0.0f;                                                  \
            _Pragma("unroll")                                                 \
            for (int ii_ = 0; ii_ < 16; ++ii_) {                              \
                float4 v_ = q_[ii_];                                          \
                s_ += v_.x * v_.x + v_.y * v_.y + v_.z * v_.z + v_.w * v_.w;  \
            }                                                                 \
            LsC[c_] = s_;                                                     \
        }                                                                     \
    } while (0)

    STAGE_CONV(0);                     // pass-0 fragments + csqr slice 0

    // ---- A fragments (MT=2): split(x) hi/lo. Lane holds
    // A[m=lrow][k=quad*8+j] for rows Rw+mt*16+lrow.
    f16x8 Ah[2][2], Al[2][2];
    float xsq = 0.0f;
#pragma unroll
    for (int mt = 0; mt < 2; ++mt) {
        const float* xr = X + (size_t)(Rw + mt * 16 + lrow) * D;
#pragma unroll
        for (int ks = 0; ks < 2; ++ks) {
            const int k0 = ks * 32 + quad * 8;
            float4 v0 = *(const float4*)(xr + k0);
            float4 v1 = *(const float4*)(xr + k0 + 4);
            float xs[8] = {v0.x, v0.y, v0.z, v0.w, v1.x, v1.y, v1.z, v1.w};
            f16x8 h, l;
#pragma unroll
            for (int j = 0; j < 8; ++j) {
                xsq += xs[j] * xs[j];
                _Float16 hh = (_Float16)xs[j];
                h[j] = hh;
                l[j] = (_Float16)(xs[j] - (float)hh);
            }
            Ah[mt][ks] = h;
            Al[mt][ks] = l;
        }
    }

    float bestd[2][4];
    int   besti[2][4];
#pragma unroll
    for (int mt = 0; mt < 2; ++mt)
#pragma unroll
        for (int r = 0; r < 4; ++r) { bestd[mt][r] = 3.0e38f; besti[mt][r] = 0; }

    __syncthreads();   // pass-0 fragments + LsC slice 0 + A ready

    // ---- 4 passes x 16 tiles. Free-run consume (R10's measured-best
    // schedule): no barriers inside a pass; __syncthreads' implicit full
    // waitcnt covers the ds_writes of the stage phase.
    for (int p = 0; p < 4; ++p) {
        if (p) {
            __syncthreads();           // all waves done reading pass p-1
            STAGE_CONV(p);
            __syncthreads();           // pass-p fragments + csqr visible
        }
#pragma unroll 4
        for (int i = 0; i < 16; ++i) {
            const f16x8* Bt = (const f16x8*)&Bbuf[i][0] + lane;
            f16x8 b0 = Bt[0], b1 = Bt[64], b2 = Bt[128], b3 = Bt[192];
            const int   c  = (p * 16 + i) * 16 + lrow;
            const float cs = LsC[c];
#pragma unroll
            for (int mt = 0; mt < 2; ++mt) {
                f32x4 acc = {cs, cs, cs, cs};
                acc = MFMA16(Ah[mt][0], b0, acc);
                acc = MFMA16(Ah[mt][1], b1, acc);
                acc = MFMA16(Al[mt][0], b0, acc);
                acc = MFMA16(Al[mt][1], b1, acc);
                acc = MFMA16(Ah[mt][0], b2, acc);
                acc = MFMA16(Ah[mt][1], b3, acc);
#pragma unroll
                for (int r = 0; r < 4; ++r) {
                    bool lt = acc[r] < bestd[mt][r];
                    bestd[mt][r] = lt ? acc[r] : bestd[mt][r];
                    besti[mt][r] = lt ? c : besti[mt][r];
                }
            }
        }
    }

    // ---- Finalize: 16-lane column reduce (lexicographic on exact ties);
    // lrow==0 lanes hold rows Rw + mt*16 + quad*4 + r (C layout:
    // row = quad*4 + r, col = lrow — verified rounds 0-12).
    float dvsum = 0.0f;
#pragma unroll
    for (int mt = 0; mt < 2; ++mt) {
#pragma unroll
        for (int r = 0; r < 4; ++r) {
            float dv = bestd[mt][r];
            int   iv = besti[mt][r];
#pragma unroll
            for (int m = 1; m < 16; m <<= 1) {
                float od = __shfl_xor(dv, m, 64);
                int   oi = __shfl_xor(iv, m, 64);
                if (od < dv || (od == dv && oi < iv)) { dv = od; iv = oi; }
            }
            if (lrow == 0) {
                const int rl = wave * 32 + mt * 16 + quad * 4 + r;  // 0..255
                ivfin[rl] = iv;
                out[1 + (size_t)N_ROWS * D + R0 + rl] = (float)iv;  // idxf
                dvsum += dv;
            }
        }
    }

    // ---- Loss partial: xsq (all lanes) + dvsum (lrow==0 lanes) reduce.
    {
        float s = xsq + dvsum;
#pragma unroll
        for (int m = 1; m < 64; m <<= 1) s += __shfl_xor(s, m, 64);
        if (lane == 0) lsum[wave] = s;
    }
    __syncthreads();                             // ivfin + lsum ready

    const float scale = 1.25f / (float)((size_t)N_ROWS * D);
    if (t == 0) {
        float L = 0.0f;
#pragma unroll
        for (int w = 0; w < 8; ++w) L += lsum[w];
        atomicAdd(out, L * scale);
    }

    // ---- Block-cooperative zq span write: dwords [R0*64, R0*64+16384) at
    // out+1. Global dword offset 1+R0*64+j is 16B-aligned iff j%4==3.
    float* p = out + 1 + (size_t)R0 * D;
#pragma unroll
    for (int i = 0; i < 8; ++i) {
        int q = i * 512 + t;        // 0..4095
        int j = 4 * q + 3;          // 3,7,...,16383
        if (q < 4095) {
            float v[4];
#pragma unroll
            for (int e = 0; e < 4; ++e) {
                int jj = j + e;     // may straddle a row boundary
                v[e] = CB[(size_t)ivfin[jj >> 6] * D + (jj & 63)];
            }
            *(float4*)(p + j) = make_float4(v[0], v[1], v[2], v[3]);
        } else if (q == 4095) {
            p[16383] = CB[(size_t)ivfin[255] * D + 63];
        }
    }
    if (t == 0) {   // head dwords j=0..2 (row 0, cols 0..2)
        const float* c0 = CB + (size_t)ivfin[0] * D;
        p[0] = c0[0];
        p[1] = c0[1];
        p[2] = c0[2];
    }
}

// ---------------------------------------------------------------------------
extern "C" void kernel_launch(void* const* d_in, const int* in_sizes, int n_in,
                              void* d_out, int out_size, void* d_ws,
                              size_t ws_size, hipStream_t stream) {
    const float* X  = (const float*)d_in[0];   // inputs  [131072,64]
    const float* CB = (const float*)d_in[1];   // codebook [1024,64]

    // Zero the loss accumulator (out[0]); graph-capture-safe async memset
    // (the harness's own reset() uses hipMemsetAsync on this stream).
    hipMemsetAsync(d_out, 0, sizeof(float), stream);

    hipLaunchKernelGGL(argmin_kernel, dim3(N_ROWS / 256), dim3(512), 0, stream,
                       X, CB, (float*)d_out);
}

// Round 14
// 147.564 us; speedup vs baseline: 1.1042x; 1.1042x over previous
//
#include <hip/hip_runtime.h>

// Problem constants
#define N_ROWS 131072    // 32*4096
#define D 64
#define K_CODES 1024

typedef _Float16 f16x8 __attribute__((ext_vector_type(8)));
typedef float    f32x4 __attribute__((ext_vector_type(4)));

#define MFMA16(a, b, c) __builtin_amdgcn_mfma_f32_16x16x32_f16((a), (b), (c), 0, 0, 0)

// ---------------------------------------------------------------------------
// ws layout: csqr[1024] f32 (4 KB) | CBf: 16384 f16x8 units (256 KB)
// 16x16x32 fragment order. CBf unit index = tile*256 + f*64 + lane,
// f in {0:hi k0-31, 1:hi k32-63, 2:lo k0-31, 3:lo k32-63}; unit holds the
// 8 halves lane needs for that MFMA B fragment:
// B[k=(lane>>4)*8+j][n=lane&15], code = tile*16 + n.
// CBf stores the hi/lo split of (-2*c); dist = |c|^2 + x.(-2c).
// (Correctness-verified rounds 2-12. R13's fused conversion REVERTED:
// VALU-converting in the stage phase sits exposed between barriers,
// +35us/dispatch; DMA staging from pre-converted CBf hides.)
// ---------------------------------------------------------------------------
__global__ __launch_bounds__(256)
void prep_kernel(const float* __restrict__ CB, _Float16* __restrict__ CBf,
                 float* __restrict__ csqr, float* __restrict__ loss) {
    const int b = blockIdx.x, t = threadIdx.x;
    if (b < 64) {
        const int unit = b * 256 + t;
        const int tile = unit >> 8;
        const int f    = (unit >> 6) & 3;
        const int lane = unit & 63;
        const int quad = lane >> 4, lrow = lane & 15;
        const int code = tile * 16 + lrow;
        const int k0   = (f & 1) * 32 + quad * 8;
        const float* src = CB + (size_t)code * D + k0;
        float4 v0 = *(const float4*)(src);
        float4 v1 = *(const float4*)(src + 4);
        float xs[8] = {v0.x, v0.y, v0.z, v0.w, v1.x, v1.y, v1.z, v1.w};
        f16x8 o;
#pragma unroll
        for (int j = 0; j < 8; ++j) {
            float sv = -2.0f * xs[j];
            _Float16 h = (_Float16)sv;
            o[j] = (f < 2) ? h : (_Float16)(sv - (float)h);
        }
        *(f16x8*)(CBf + (size_t)unit * 8) = o;
    } else {
        if (t == 0) *loss = 0.0f;
        for (int k = t; k < K_CODES; k += 256) {
            const float4* p = (const float4*)(CB + (size_t)k * D);
            float s = 0.0f;
#pragma unroll
            for (int i = 0; i < 16; ++i) {
                float4 v = p[i];
                s += v.x * v.x + v.y * v.y + v.z * v.z + v.w * v.w;
            }
            csqr[k] = s;
        }
    }
}

// ---------------------------------------------------------------------------
// Direct global->LDS 16B copy (lane-linear dest: wave-uniform base + lane*16).
// ---------------------------------------------------------------------------
__device__ __forceinline__ void gload_lds16(const void* g, void* l) {
    __builtin_amdgcn_global_load_lds(
        (const __attribute__((address_space(1))) void*)g,
        (__attribute__((address_space(3))) void*)l,
        16, 0, 0);
}

// ---------------------------------------------------------------------------
// K1 (R10 free-run + 128-reg COMPILER self-pipelining): the one untested
// cell. R12 tested manual pinning at 128 regs (regressed — m141); R10's
// measured-best free-run loop ran at the 64-reg cap = room for exactly ONE
// tile's B fragments -> compiler's scheduler (which emits near-optimal
// fine-grained lgkmcnt when it has registers, m97) was structurally
// depth-1. CHANGE vs R10 (64.9us): __launch_bounds__(512,2) -> 128-reg
// budget, 16-tile loop FULLY unrolled, zero manual fences — compiler
// chooses its own read-ahead depth. Occupancy unchanged by design (LDS
// 69 KB -> 2 blocks/CU; 16 waves/CU = 4/SIMD at vgpr<=128; grid 512).
// Macro-structure = R10 verbatim: 4 passes x 16 tiles, single 64 KB
// buffer staged via 8 gload_lds/thread, free-run consume, 8 barriers
// total; MT=2; split numerics (hh,hh,lh,lh,hl,hl; ll ~2^-24 dropped);
// acc-init=csqr; first-min tie-break (codes ascend with (p,tile):
// strict <; 16-lane column reduce index-lexicographic); 256-row zq
// epilogue. All correctness-verified rounds 2-12.
// ---------------------------------------------------------------------------
__global__ __launch_bounds__(512, 2)
void argmin_kernel(const float* __restrict__ X,
                   const _Float16* __restrict__ CBf,
                   const float* __restrict__ csqr,
                   const float* __restrict__ CB,
                   float* __restrict__ out) {
    __shared__ _Float16 Bbuf[16][2048];   // 64 KB: 16 tiles x 4 KB (one pass)
    __shared__ float LsC[K_CODES];        // csqr copy, 4 KB
    __shared__ int   ivfin[256];
    __shared__ float lsum[8];

    const int t    = threadIdx.x;         // 0..511
    const int wave = t >> 6;              // 0..7
    const int lane = t & 63;
    const int quad = lane >> 4;
    const int lrow = lane & 15;
    const int R0   = blockIdx.x * 256;
    const int Rw   = R0 + wave * 32;      // this wave's 32 rows

// Stage pass p (16 tiles = 4096 units of 16B): 512 threads x 8 gload_lds.
#define STAGE(p_)                                                             \
    do {                                                                      \
        _Pragma("unroll")                                                     \
        for (int i_ = 0; i_ < 8; ++i_) {                                      \
            const int u_ = i_ * 512 + t;                                      \
            const f16x8* gp_ =                                                \
                (const f16x8*)CBf + (size_t)((p_) * 4096 + u_);               \
            gload_lds16((const void*)gp_,                                     \
                        (void*)((char*)&Bbuf[0][0] + (size_t)u_ * 16));       \
        }                                                                     \
    } while (0)

    STAGE(0);                          // pass-0 B in flight ASAP

    // csqr -> LDS (covered by the prologue __syncthreads).
    if (t < 256) ((float4*)LsC)[t] = ((const float4*)csqr)[t];

    // ---- A fragments (MT=2): split(x) hi/lo. Lane holds
    // A[m=lrow][k=quad*8+j] for rows Rw+mt*16+lrow; quads x ks cover the 64
    // columns -> per-wave xsq counts each of its 32x64 elements once.
    f16x8 Ah[2][2], Al[2][2];
    float xsq = 0.0f;
#pragma unroll
    for (int mt = 0; mt < 2; ++mt) {
        const float* xr = X + (size_t)(Rw + mt * 16 + lrow) * D;
#pragma unroll
        for (int ks = 0; ks < 2; ++ks) {
            const int k0 = ks * 32 + quad * 8;
            float4 v0 = *(const float4*)(xr + k0);
            float4 v1 = *(const float4*)(xr + k0 + 4);
            float xs[8] = {v0.x, v0.y, v0.z, v0.w, v1.x, v1.y, v1.z, v1.w};
            f16x8 h, l;
#pragma unroll
            for (int j = 0; j < 8; ++j) {
                xsq += xs[j] * xs[j];
                _Float16 hh = (_Float16)xs[j];
                h[j] = hh;
                l[j] = (_Float16)(xs[j] - (float)hh);
            }
            Ah[mt][ks] = h;
            Al[mt][ks] = l;
        }
    }

    float bestd[2][4];
    int   besti[2][4];
#pragma unroll
    for (int mt = 0; mt < 2; ++mt)
#pragma unroll
        for (int r = 0; r < 4; ++r) { bestd[mt][r] = 3.0e38f; besti[mt][r] = 0; }

    __syncthreads();   // pass-0 B + LsC + A ready (full drain, prologue)

    // ---- 4 passes x 16 tiles. Fully unrolled free-run consume: compiler
    // pipelines ds_read <-> MFMA across tiles with the 128-reg budget.
    for (int p = 0; p < 4; ++p) {
        if (p) {
            __syncthreads();           // all waves done reading pass p-1
            STAGE(p);
            asm volatile("s_waitcnt vmcnt(0)" ::: "memory");
            __syncthreads();           // pass-p B visible to all waves
        }
#pragma unroll
        for (int i = 0; i < 16; ++i) {
            const f16x8* Bt = (const f16x8*)&Bbuf[i][0] + lane;
            f16x8 b0 = Bt[0], b1 = Bt[64], b2 = Bt[128], b3 = Bt[192];
            const int   c  = (p * 16 + i) * 16 + lrow;
            const float cs = LsC[c];
#pragma unroll
            for (int mt = 0; mt < 2; ++mt) {
                f32x4 acc = {cs, cs, cs, cs};
                acc = MFMA16(Ah[mt][0], b0, acc);
                acc = MFMA16(Ah[mt][1], b1, acc);
                acc = MFMA16(Al[mt][0], b0, acc);
                acc = MFMA16(Al[mt][1], b1, acc);
                acc = MFMA16(Ah[mt][0], b2, acc);
                acc = MFMA16(Ah[mt][1], b3, acc);
#pragma unroll
                for (int r = 0; r < 4; ++r) {
                    bool lt = acc[r] < bestd[mt][r];
                    bestd[mt][r] = lt ? acc[r] : bestd[mt][r];
                    besti[mt][r] = lt ? c : besti[mt][r];
                }
            }
        }
    }

    // ---- Finalize: 16-lane column reduce (lexicographic on exact ties);
    // lrow==0 lanes hold rows Rw + mt*16 + quad*4 + r (C layout:
    // row = quad*4 + r, col = lrow — verified rounds 0-13).
    float dvsum = 0.0f;
#pragma unroll
    for (int mt = 0; mt < 2; ++mt) {
#pragma unroll
        for (int r = 0; r < 4; ++r) {
            float dv = bestd[mt][r];
            int   iv = besti[mt][r];
#pragma unroll
            for (int m = 1; m < 16; m <<= 1) {
                float od = __shfl_xor(dv, m, 64);
                int   oi = __shfl_xor(iv, m, 64);
                if (od < dv || (od == dv && oi < iv)) { dv = od; iv = oi; }
            }
            if (lrow == 0) {
                const int rl = wave * 32 + mt * 16 + quad * 4 + r;  // 0..255
                ivfin[rl] = iv;
                out[1 + (size_t)N_ROWS * D + R0 + rl] = (float)iv;  // idxf
                dvsum += dv;
            }
        }
    }

    // ---- Loss partial: xsq (all lanes) + dvsum (lrow==0 lanes) reduce.
    {
        float s = xsq + dvsum;
#pragma unroll
        for (int m = 1; m < 64; m <<= 1) s += __shfl_xor(s, m, 64);
        if (lane == 0) lsum[wave] = s;
    }
    __syncthreads();                             // ivfin + lsum ready

    const float scale = 1.25f / (float)((size_t)N_ROWS * D);
    if (t == 0) {
        float L = 0.0f;
#pragma unroll
        for (int w = 0; w < 8; ++w) L += lsum[w];
        atomicAdd(out, L * scale);
    }

    // ---- Block-cooperative zq span write: dwords [R0*64, R0*64+16384) at
    // out+1. Global dword offset 1+R0*64+j is 16B-aligned iff j%4==3.
    float* p = out + 1 + (size_t)R0 * D;
#pragma unroll
    for (int i = 0; i < 8; ++i) {
        int q = i * 512 + t;        // 0..4095
        int j = 4 * q + 3;          // 3,7,...,16383
        if (q < 4095) {
            float v[4];
#pragma unroll
            for (int e = 0; e < 4; ++e) {
                int jj = j + e;     // may straddle a row boundary
                v[e] = CB[(size_t)ivfin[jj >> 6] * D + (jj & 63)];
            }
            *(float4*)(p + j) = make_float4(v[0], v[1], v[2], v[3]);
        } else if (q == 4095) {
            p[16383] = CB[(size_t)ivfin[255] * D + 63];
        }
    }
    if (t == 0) {   // head dwords j=0..2 (row 0, cols 0..2)
        const float* c0 = CB + (size_t)ivfin[0] * D;
        p[0] = c0[0];
        p[1] = c0[1];
        p[2] = c0[2];
    }
}

// ---------------------------------------------------------------------------
extern "C" void kernel_launch(void* const* d_in, const int* in_sizes, int n_in,
                              void* d_out, int out_size, void* d_ws,
                              size_t ws_size, hipStream_t stream) {
    const float* X  = (const float*)d_in[0];   // inputs  [131072,64]
    const float* CB = (const float*)d_in[1];   // codebook [1024,64]

    float*    csqr = (float*)d_ws;                      // 4 KB
    _Float16* CBf  = (_Float16*)((char*)d_ws + 4096);   // 256 KB

    hipLaunchKernelGGL(prep_kernel, dim3(65), dim3(256), 0, stream,
                       CB, CBf, csqr, (float*)d_out);
    hipLaunchKernelGGL(argmin_kernel, dim3(N_ROWS / 256), dim3(512), 0, stream,
                       X, CBf, csqr, CB, (float*)d_out);
}